// Round 3
// baseline (977.179 us; speedup 1.0000x reference)
//
#include <hip/hip_runtime.h>

#define NN 100000
#define NE 1200000
#define NF 64
#define NH 256
#define NC 40
#define ORDER_C 8

// ---- bf16 helpers (RTNE pack, cheap unpack) ----
__device__ __forceinline__ unsigned bf16r(float x) {
    unsigned u = __float_as_uint(x);
    return (u + 0x7FFFu + ((u >> 16) & 1u)) >> 16;
}
__device__ __forceinline__ unsigned packbf(float lo, float hi) {
    return bf16r(lo) | (bf16r(hi) << 16);
}
__device__ __forceinline__ float bflo(unsigned u) { return __uint_as_float(u << 16); }
__device__ __forceinline__ float bfhi(unsigned u) { return __uint_as_float(u & 0xFFFF0000u); }

// ---------------- CSR build ----------------

static __global__ __launch_bounds__(256) void k_count(const int* __restrict__ rows,
                                                      int* __restrict__ cnt, int E)
{
    int i = blockIdx.x * 256 + threadIdx.x;
    if (i < E) atomicAdd(&cnt[rows[i]], 1);
}

static __global__ __launch_bounds__(256) void k_dinv(const int* __restrict__ cnt,
                                                     float* __restrict__ dinv, int n)
{
    int i = blockIdx.x * 256 + threadIdx.x;
    if (i < n) dinv[i] = rsqrtf((float)(cnt[i] + 1));  // +1 self-loop
}

static __global__ __launch_bounds__(1024) void k_scan(const int* __restrict__ cnt,
                                                      int* __restrict__ rp, int n)
{
    __shared__ int sums[1024];
    int tid = threadIdx.x;
    int per = (n + 1023) >> 10;
    int beg = tid * per;
    int end = beg + per; if (end > n) end = n;
    int s = 0;
    for (int i = beg; i < end; ++i) s += cnt[i];
    sums[tid] = s;
    __syncthreads();
    for (int off = 1; off < 1024; off <<= 1) {
        int v = (tid >= off) ? sums[tid - off] : 0;
        __syncthreads();
        sums[tid] += v;
        __syncthreads();
    }
    int run = (tid == 0) ? 0 : sums[tid - 1];
    for (int i = beg; i < end; ++i) { rp[i] = run; run += cnt[i]; }
    if (beg < n && end == n) rp[n] = run;
}

static __global__ __launch_bounds__(256) void k_scatter(const int* __restrict__ rows,
                                                        const int* __restrict__ cols,
                                                        const int* __restrict__ rp,
                                                        int* __restrict__ fill,
                                                        const float* __restrict__ dinv,
                                                        int2* __restrict__ colw, int E)
{
    int i = blockIdx.x * 256 + threadIdx.x;
    if (i < E) {
        int r = rows[i], c = cols[i];
        int pos = rp[r] + atomicAdd(&fill[r], 1);
        colw[pos] = make_int2(c, __float_as_int(dinv[c]));
    }
}

// ---------------- init: y = 0.5*x (f32) ; h = bf16(0.5*x) ----------------
// one thread per 8-feature chunk

static __global__ __launch_bounds__(256) void k_init(const float4* __restrict__ x4,
                                                     float4* __restrict__ y4,
                                                     uint4* __restrict__ hb, int nchunk)
{
    int i = blockIdx.x * 256 + threadIdx.x;
    if (i >= nchunk) return;
    float4 a = x4[i * 2], b = x4[i * 2 + 1];
    a.x *= 0.5f; a.y *= 0.5f; a.z *= 0.5f; a.w *= 0.5f;
    b.x *= 0.5f; b.y *= 0.5f; b.z *= 0.5f; b.w *= 0.5f;
    y4[i * 2] = a; y4[i * 2 + 1] = b;
    hb[i] = make_uint4(packbf(a.x, a.y), packbf(a.z, a.w),
                       packbf(b.x, b.y), packbf(b.z, b.w));
}

// ---------------- SpMM: wave per row, 8 lanes x 16B(bf16) per edge, 8 edges in flight ----

static __global__ __launch_bounds__(256) void k_spmm(const uint4* __restrict__ hb,
                                                     uint4* __restrict__ ho,
                                                     float4* __restrict__ y4,
                                                     const int* __restrict__ rp,
                                                     const int2* __restrict__ colw,
                                                     const float* __restrict__ dinv, int n)
{
    int wave = (blockIdx.x * 256 + threadIdx.x) >> 6;
    int lane = threadIdx.x & 63;
    if (wave >= n) return;
    int f = lane & 7;   // 16B chunk (8 feats) within the 128B bf16 row
    int q = lane >> 3;  // edge slot (8 edges concurrently)
    int s = rp[wave], e = rp[wave + 1];
    float acc[8] = {0.f, 0.f, 0.f, 0.f, 0.f, 0.f, 0.f, 0.f};
    for (int i = s + q; i < e; i += 8) {
        int2 cw = colw[i];
        float w = __int_as_float(cw.y);
        uint4 hv = hb[(size_t)cw.x * 8 + f];
        acc[0] = fmaf(w, bflo(hv.x), acc[0]);
        acc[1] = fmaf(w, bfhi(hv.x), acc[1]);
        acc[2] = fmaf(w, bflo(hv.y), acc[2]);
        acc[3] = fmaf(w, bfhi(hv.y), acc[3]);
        acc[4] = fmaf(w, bflo(hv.z), acc[4]);
        acc[5] = fmaf(w, bfhi(hv.z), acc[5]);
        acc[6] = fmaf(w, bflo(hv.w), acc[6]);
        acc[7] = fmaf(w, bfhi(hv.w), acc[7]);
    }
    #pragma unroll
    for (int m = 8; m <= 32; m <<= 1) {
        #pragma unroll
        for (int j = 0; j < 8; ++j) acc[j] += __shfl_xor(acc[j], m);
    }
    if (q == 0) {
        float di = dinv[wave];
        uint4 hs = hb[(size_t)wave * 8 + f];
        float v0 = di * fmaf(di, bflo(hs.x), acc[0]);
        float v1 = di * fmaf(di, bfhi(hs.x), acc[1]);
        float v2 = di * fmaf(di, bflo(hs.y), acc[2]);
        float v3 = di * fmaf(di, bfhi(hs.y), acc[3]);
        float v4 = di * fmaf(di, bflo(hs.z), acc[4]);
        float v5 = di * fmaf(di, bfhi(hs.z), acc[5]);
        float v6 = di * fmaf(di, bflo(hs.w), acc[6]);
        float v7 = di * fmaf(di, bfhi(hs.w), acc[7]);
        ho[(size_t)wave * 8 + f] = make_uint4(packbf(v0, v1), packbf(v2, v3),
                                              packbf(v4, v5), packbf(v6, v7));
        size_t yi = (size_t)wave * 16 + f * 2;
        float4 ya = y4[yi], yb = y4[yi + 1];
        ya.x += v0; ya.y += v1; ya.z += v2; ya.w += v3;
        yb.x += v4; yb.y += v5; yb.z += v6; yb.w += v7;
        y4[yi] = ya; y4[yi + 1] = yb;
    }
}

// ---------------- fused MLP: lane = (row 8, hidden-part 8), 12500 waves ----------------
// out[row] = relu((y[row]/9) @ W1 + b1) @ W2 + b2

static __global__ __launch_bounds__(256) void k_mlp(const float4* __restrict__ y4,
                                                    const float* __restrict__ W1,
                                                    const float* __restrict__ b1,
                                                    const float* __restrict__ W2,
                                                    const float* __restrict__ b2,
                                                    float* __restrict__ out, int n)
{
    int tid  = blockIdx.x * 256 + threadIdx.x;
    int lane = threadIdx.x & 63;
    int wv   = tid >> 6;
    int r8   = lane & 7;
    int part = lane >> 3;         // hidden chunk of 32
    int row  = wv * 8 + r8;
    bool valid = row < n;
    const float S = 1.f / 9.f;

    // layer 1: acc[c] for hidden units part*32 + c
    float acc[32];
    const float4* b14 = (const float4*)b1;
    #pragma unroll
    for (int c4 = 0; c4 < 8; ++c4) {
        float4 b = b14[part * 8 + c4];
        acc[c4 * 4 + 0] = b.x; acc[c4 * 4 + 1] = b.y;
        acc[c4 * 4 + 2] = b.z; acc[c4 * 4 + 3] = b.w;
    }
    const float4* W14 = (const float4*)W1;
    const float4* yrow = y4 + (size_t)row * 16;
    for (int kb = 0; kb < 16; ++kb) {
        float4 yv = valid ? yrow[kb] : make_float4(0.f, 0.f, 0.f, 0.f);
        yv.x *= S; yv.y *= S; yv.z *= S; yv.w *= S;
        #pragma unroll
        for (int j = 0; j < 4; ++j) {
            float yj = (j == 0) ? yv.x : (j == 1) ? yv.y : (j == 2) ? yv.z : yv.w;
            const float4* w1r = W14 + (size_t)(kb * 4 + j) * 64 + part * 8;
            #pragma unroll
            for (int c4 = 0; c4 < 8; ++c4) {
                float4 w = w1r[c4];
                acc[c4 * 4 + 0] = fmaf(yj, w.x, acc[c4 * 4 + 0]);
                acc[c4 * 4 + 1] = fmaf(yj, w.y, acc[c4 * 4 + 1]);
                acc[c4 * 4 + 2] = fmaf(yj, w.z, acc[c4 * 4 + 2]);
                acc[c4 * 4 + 3] = fmaf(yj, w.w, acc[c4 * 4 + 3]);
            }
        }
    }

    // layer 2: partial o[40] over this lane's 32 hidden units
    float o[40];
    #pragma unroll
    for (int j = 0; j < 40; ++j) o[j] = 0.f;
    const float4* W24 = (const float4*)W2;
    for (int c = 0; c < 32; ++c) {
        float hv = fmaxf(acc[c], 0.f);
        const float4* w2r = W24 + (size_t)(part * 32 + c) * 10;
        #pragma unroll
        for (int t = 0; t < 10; ++t) {
            float4 w = w2r[t];
            o[t * 4 + 0] = fmaf(hv, w.x, o[t * 4 + 0]);
            o[t * 4 + 1] = fmaf(hv, w.y, o[t * 4 + 1]);
            o[t * 4 + 2] = fmaf(hv, w.z, o[t * 4 + 2]);
            o[t * 4 + 3] = fmaf(hv, w.w, o[t * 4 + 3]);
        }
    }
    // reduce across the 8 parts (lane bits 3,4,5)
    #pragma unroll
    for (int m = 8; m <= 32; m <<= 1) {
        #pragma unroll
        for (int j = 0; j < 40; ++j) o[j] += __shfl_xor(o[j], m);
    }
    if (part == 0 && valid) {
        const float4* b24 = (const float4*)b2;
        float4* o4 = (float4*)out + (size_t)row * 10;
        #pragma unroll
        for (int t = 0; t < 10; ++t) {
            float4 b = b24[t];
            float4 v;
            v.x = o[t * 4 + 0] + b.x; v.y = o[t * 4 + 1] + b.y;
            v.z = o[t * 4 + 2] + b.z; v.w = o[t * 4 + 3] + b.w;
            o4[t] = v;
        }
    }
}

// ---------------- launch ----------------

extern "C" void kernel_launch(void* const* d_in, const int* in_sizes, int n_in,
                              void* d_out, int out_size, void* d_ws, size_t ws_size,
                              hipStream_t stream)
{
    const float* x  = (const float*)d_in[0];
    const int*   ei = (const int*)d_in[1];
    const float* W1 = (const float*)d_in[2];
    const float* b1 = (const float*)d_in[3];
    const float* W2 = (const float*)d_in[4];
    const float* b2 = (const float*)d_in[5];
    float* out = (float*)d_out;

    const int n = NN, E = NE;

    char* ws = (char*)d_ws;
    size_t off = 0;
    auto alloc = [&](size_t bytes) -> void* {
        void* p = ws + off;
        off = (off + bytes + 255) & ~(size_t)255;
        return p;
    };
    int*   cnt  = (int*)  alloc((size_t)n * 4);
    int*   fill = (int*)  alloc((size_t)n * 4);
    int*   rp   = (int*)  alloc((size_t)(n + 1) * 4);
    float* dinv = (float*)alloc((size_t)n * 4);
    int2*  colw = (int2*) alloc((size_t)E * 8);
    uint4* ha   = (uint4*)alloc((size_t)n * NF * 2);   // bf16 h ping
    uint4* hbuf = (uint4*)alloc((size_t)n * NF * 2);   // bf16 h pong
    float* y    = (float*)alloc((size_t)n * NF * 4);   // f32 accumulator

    hipMemsetAsync(cnt, 0, (size_t)n * 4, stream);
    hipMemsetAsync(fill, 0, (size_t)n * 4, stream);

    const int* rows = ei;
    const int* cols = ei + E;

    k_count  <<<(E + 255) / 256, 256, 0, stream>>>(rows, cnt, E);
    k_dinv   <<<(n + 255) / 256, 256, 0, stream>>>(cnt, dinv, n);
    k_scan   <<<1, 1024, 0, stream>>>(cnt, rp, n);
    k_scatter<<<(E + 255) / 256, 256, 0, stream>>>(rows, cols, rp, fill, dinv, colw, E);

    int nchunk = n * 8;  // 8-feature chunks
    k_init<<<(nchunk + 255) / 256, 256, 0, stream>>>((const float4*)x, (float4*)y, ha, nchunk);

    uint4* cur = ha;
    uint4* nxt = hbuf;
    for (int it = 0; it < ORDER_C; ++it) {
        k_spmm<<<(n * 64 + 255) / 256, 256, 0, stream>>>(cur, nxt, (float4*)y,
                                                         rp, colw, dinv, n);
        uint4* t = cur; cur = nxt; nxt = t;
    }

    int mlp_threads = ((n + 7) / 8) * 64;
    k_mlp<<<(mlp_threads + 255) / 256, 256, 0, stream>>>((const float4*)y, W1, b1, W2, b2, out, n);
}

// Round 4
// 692.226 us; speedup vs baseline: 1.4116x; 1.4116x over previous
//
#include <hip/hip_runtime.h>

#define NN 100000
#define NE 1200000
#define NF 64
#define NH 256
#define NC 40
#define ORDER_C 8

// ---- bf16 helpers (RTNE pack, cheap unpack) ----
__device__ __forceinline__ unsigned bf16r(float x) {
    unsigned u = __float_as_uint(x);
    return (u + 0x7FFFu + ((u >> 16) & 1u)) >> 16;
}
__device__ __forceinline__ unsigned packbf(float lo, float hi) {
    return bf16r(lo) | (bf16r(hi) << 16);
}
__device__ __forceinline__ float bflo(unsigned u) { return __uint_as_float(u << 16); }
__device__ __forceinline__ float bfhi(unsigned u) { return __uint_as_float(u & 0xFFFF0000u); }

// ---------------- CSR build ----------------

static __global__ __launch_bounds__(256) void k_count(const int* __restrict__ rows,
                                                      int* __restrict__ cnt, int E)
{
    int i = blockIdx.x * 256 + threadIdx.x;
    if (i < E) atomicAdd(&cnt[rows[i]], 1);
}

static __global__ __launch_bounds__(256) void k_dinv(const int* __restrict__ cnt,
                                                     float* __restrict__ dinv, int n)
{
    int i = blockIdx.x * 256 + threadIdx.x;
    if (i < n) dinv[i] = rsqrtf((float)(cnt[i] + 1));  // +1 self-loop
}

static __global__ __launch_bounds__(1024) void k_scan(const int* __restrict__ cnt,
                                                      int* __restrict__ rp, int n)
{
    __shared__ int sums[1024];
    int tid = threadIdx.x;
    int per = (n + 1023) >> 10;
    int beg = tid * per;
    int end = beg + per; if (end > n) end = n;
    int s = 0;
    for (int i = beg; i < end; ++i) s += cnt[i];
    sums[tid] = s;
    __syncthreads();
    for (int off = 1; off < 1024; off <<= 1) {
        int v = (tid >= off) ? sums[tid - off] : 0;
        __syncthreads();
        sums[tid] += v;
        __syncthreads();
    }
    int run = (tid == 0) ? 0 : sums[tid - 1];
    for (int i = beg; i < end; ++i) { rp[i] = run; run += cnt[i]; }
    if (beg < n && end == n) rp[n] = run;
}

static __global__ __launch_bounds__(256) void k_scatter(const int* __restrict__ rows,
                                                        const int* __restrict__ cols,
                                                        const int* __restrict__ rp,
                                                        int* __restrict__ fill,
                                                        const float* __restrict__ dinv,
                                                        int2* __restrict__ colw, int E)
{
    int i = blockIdx.x * 256 + threadIdx.x;
    if (i < E) {
        int r = rows[i], c = cols[i];
        int pos = rp[r] + atomicAdd(&fill[r], 1);
        colw[pos] = make_int2(c, __float_as_int(dinv[c]));
    }
}

// ---------------- init: y = 0.5*x (f32) ; h = bf16(0.5*x) ----------------

static __global__ __launch_bounds__(256) void k_init(const float4* __restrict__ x4,
                                                     float4* __restrict__ y4,
                                                     uint4* __restrict__ hb, int nchunk)
{
    int i = blockIdx.x * 256 + threadIdx.x;
    if (i >= nchunk) return;
    float4 a = x4[i * 2], b = x4[i * 2 + 1];
    a.x *= 0.5f; a.y *= 0.5f; a.z *= 0.5f; a.w *= 0.5f;
    b.x *= 0.5f; b.y *= 0.5f; b.z *= 0.5f; b.w *= 0.5f;
    y4[i * 2] = a; y4[i * 2 + 1] = b;
    hb[i] = make_uint4(packbf(a.x, a.y), packbf(a.z, a.w),
                       packbf(b.x, b.y), packbf(b.z, b.w));
}

// ---------------- SpMM: wave = 2 rows, 8 edge slots x 8 feat-lanes each ----------------

static __global__ __launch_bounds__(256) void k_spmm(const uint4* __restrict__ hb,
                                                     uint4* __restrict__ ho,
                                                     float4* __restrict__ y4,
                                                     const int* __restrict__ rp,
                                                     const int2* __restrict__ colw,
                                                     const float* __restrict__ dinv, int n)
{
    int wid = (blockIdx.x * 256 + threadIdx.x) >> 6;
    int lane = threadIdx.x & 63;
    int r0 = wid * 2, r1 = r0 + 1;
    if (r0 >= n) return;
    bool has1 = r1 < n;
    int f = lane & 7;   // 16B chunk within the 128B bf16 row
    int q = lane >> 3;  // edge slot
    int s0 = rp[r0], e0 = rp[r0 + 1];
    int s1 = has1 ? rp[r1] : 0;
    int e1 = has1 ? rp[r1 + 1] : 0;
    float a0[8] = {0,0,0,0,0,0,0,0};
    float a1[8] = {0,0,0,0,0,0,0,0};
    int i0 = s0 + q, i1 = s1 + q;
    while (i0 < e0 || i1 < e1) {
        int2 cw0, cw1; uint4 h0, h1;
        bool p0 = i0 < e0, p1 = i1 < e1;
        if (p0) cw0 = colw[i0];
        if (p1) cw1 = colw[i1];
        if (p0) h0 = hb[(size_t)cw0.x * 8 + f];
        if (p1) h1 = hb[(size_t)cw1.x * 8 + f];
        if (p0) {
            float w = __int_as_float(cw0.y);
            a0[0] = fmaf(w, bflo(h0.x), a0[0]); a0[1] = fmaf(w, bfhi(h0.x), a0[1]);
            a0[2] = fmaf(w, bflo(h0.y), a0[2]); a0[3] = fmaf(w, bfhi(h0.y), a0[3]);
            a0[4] = fmaf(w, bflo(h0.z), a0[4]); a0[5] = fmaf(w, bfhi(h0.z), a0[5]);
            a0[6] = fmaf(w, bflo(h0.w), a0[6]); a0[7] = fmaf(w, bfhi(h0.w), a0[7]);
        }
        if (p1) {
            float w = __int_as_float(cw1.y);
            a1[0] = fmaf(w, bflo(h1.x), a1[0]); a1[1] = fmaf(w, bfhi(h1.x), a1[1]);
            a1[2] = fmaf(w, bflo(h1.y), a1[2]); a1[3] = fmaf(w, bfhi(h1.y), a1[3]);
            a1[4] = fmaf(w, bflo(h1.z), a1[4]); a1[5] = fmaf(w, bfhi(h1.z), a1[5]);
            a1[6] = fmaf(w, bflo(h1.w), a1[6]); a1[7] = fmaf(w, bfhi(h1.w), a1[7]);
        }
        i0 += 8; i1 += 8;
    }
    #pragma unroll
    for (int m = 8; m <= 32; m <<= 1) {
        #pragma unroll
        for (int j = 0; j < 8; ++j) {
            a0[j] += __shfl_xor(a0[j], m);
            a1[j] += __shfl_xor(a1[j], m);
        }
    }
    if (q <= 1 && (q == 0 || has1)) {
        int row = q ? r1 : r0;
        float v[8];
        #pragma unroll
        for (int j = 0; j < 8; ++j) v[j] = q ? a1[j] : a0[j];
        float di = dinv[row];
        uint4 hs = hb[(size_t)row * 8 + f];
        float v0 = di * fmaf(di, bflo(hs.x), v[0]);
        float v1 = di * fmaf(di, bfhi(hs.x), v[1]);
        float v2 = di * fmaf(di, bflo(hs.y), v[2]);
        float v3 = di * fmaf(di, bfhi(hs.y), v[3]);
        float v4 = di * fmaf(di, bflo(hs.z), v[4]);
        float v5 = di * fmaf(di, bfhi(hs.z), v[5]);
        float v6 = di * fmaf(di, bflo(hs.w), v[6]);
        float v7 = di * fmaf(di, bfhi(hs.w), v[7]);
        ho[(size_t)row * 8 + f] = make_uint4(packbf(v0, v1), packbf(v2, v3),
                                             packbf(v4, v5), packbf(v6, v7));
        size_t yi = (size_t)row * 16 + f * 2;
        float4 ya = y4[yi], yb = y4[yi + 1];
        ya.x += v0; ya.y += v1; ya.z += v2; ya.w += v3;
        yb.x += v4; yb.y += v5; yb.z += v6; yb.w += v7;
        y4[yi] = ya; y4[yi + 1] = yb;
    }
}

// ---------------- fused MLP: 64 rows/block, LDS-staged, broadcast weights ----------------
// out[row] = relu((y[row]/9) @ W1 + b1) @ W2 + b2

static __global__ __launch_bounds__(256) void k_mlp(const float4* __restrict__ y4,
                                                    const float* __restrict__ W1,
                                                    const float* __restrict__ b1,
                                                    const float* __restrict__ W2,
                                                    const float* __restrict__ b2,
                                                    float* __restrict__ out, int n)
{
    __shared__ float ysT[64][68];        // [feat][row], f32, 17.4 KB
    __shared__ unsigned short hs[64][268]; // [row][hid] bf16, 34.3 KB
    const float S = 1.f / 9.f;
    int t = threadIdx.x;
    int base = blockIdx.x * 64;

    // ---- load y tile, transpose into ysT (scale folded) ----
    {
        int r = t >> 2, fq = t & 3;       // 4 threads per row, 4 float4 each
        int row = base + r;
        bool valid = row < n;
        #pragma unroll
        for (int j = 0; j < 4; ++j) {
            float4 v = valid ? y4[(size_t)row * 16 + fq * 4 + j]
                             : make_float4(0.f, 0.f, 0.f, 0.f);
            ysT[fq * 16 + j * 4 + 0][r] = v.x * S;
            ysT[fq * 16 + j * 4 + 1][r] = v.y * S;
            ysT[fq * 16 + j * 4 + 2][r] = v.z * S;
            ysT[fq * 16 + j * 4 + 3][r] = v.w * S;
        }
    }
    __syncthreads();

    // ---- layer 1: wave w -> rows w*16..+15 ; lane c -> hid c*4..+3 ----
    int c = t & 63;
    int w = t >> 6;
    int w16 = w * 16;
    {
        float4 acc[16];
        float4 bb = ((const float4*)b1)[c];
        #pragma unroll
        for (int r = 0; r < 16; ++r) acc[r] = bb;
        const float4* W14 = (const float4*)W1;
        #pragma unroll 2
        for (int k = 0; k < 64; ++k) {
            float4 wv = W14[k * 64 + c];
            const float4* yp = (const float4*)&ysT[k][w16];  // broadcast
            float4 y0 = yp[0], y1 = yp[1], y2 = yp[2], y3 = yp[3];
            #pragma unroll
            for (int j = 0; j < 4; ++j) {
                float ya = (j == 0) ? y0.x : (j == 1) ? y0.y : (j == 2) ? y0.z : y0.w;
                acc[j].x = fmaf(ya, wv.x, acc[j].x);
                acc[j].y = fmaf(ya, wv.y, acc[j].y);
                acc[j].z = fmaf(ya, wv.z, acc[j].z);
                acc[j].w = fmaf(ya, wv.w, acc[j].w);
            }
            #pragma unroll
            for (int j = 0; j < 4; ++j) {
                float ya = (j == 0) ? y1.x : (j == 1) ? y1.y : (j == 2) ? y1.z : y1.w;
                acc[4 + j].x = fmaf(ya, wv.x, acc[4 + j].x);
                acc[4 + j].y = fmaf(ya, wv.y, acc[4 + j].y);
                acc[4 + j].z = fmaf(ya, wv.z, acc[4 + j].z);
                acc[4 + j].w = fmaf(ya, wv.w, acc[4 + j].w);
            }
            #pragma unroll
            for (int j = 0; j < 4; ++j) {
                float ya = (j == 0) ? y2.x : (j == 1) ? y2.y : (j == 2) ? y2.z : y2.w;
                acc[8 + j].x = fmaf(ya, wv.x, acc[8 + j].x);
                acc[8 + j].y = fmaf(ya, wv.y, acc[8 + j].y);
                acc[8 + j].z = fmaf(ya, wv.z, acc[8 + j].z);
                acc[8 + j].w = fmaf(ya, wv.w, acc[8 + j].w);
            }
            #pragma unroll
            for (int j = 0; j < 4; ++j) {
                float ya = (j == 0) ? y3.x : (j == 1) ? y3.y : (j == 2) ? y3.z : y3.w;
                acc[12 + j].x = fmaf(ya, wv.x, acc[12 + j].x);
                acc[12 + j].y = fmaf(ya, wv.y, acc[12 + j].y);
                acc[12 + j].z = fmaf(ya, wv.z, acc[12 + j].z);
                acc[12 + j].w = fmaf(ya, wv.w, acc[12 + j].w);
            }
        }
        // relu + pack bf16 into hs
        #pragma unroll
        for (int r = 0; r < 16; ++r) {
            float hx = fmaxf(acc[r].x, 0.f), hy = fmaxf(acc[r].y, 0.f);
            float hz = fmaxf(acc[r].z, 0.f), hw = fmaxf(acc[r].w, 0.f);
            uint2 p = make_uint2(packbf(hx, hy), packbf(hz, hw));
            *(uint2*)&hs[w16 + r][c * 4] = p;
        }
    }
    __syncthreads();

    // ---- layer 2: lane = row, wave -> classes wj*10..+9 ; W2 via scalar loads ----
    {
        int r2 = t & 63;
        int wj = __builtin_amdgcn_readfirstlane(t >> 6);
        int row = base + r2;
        float o[10];
        #pragma unroll
        for (int j = 0; j < 10; ++j) o[j] = b2[wj * 10 + j];
        #pragma unroll 2
        for (int k4 = 0; k4 < 64; ++k4) {
            uint2 hv = *(const uint2*)&hs[r2][k4 * 4];
            float h0 = bflo(hv.x), h1 = bfhi(hv.x);
            float h2 = bflo(hv.y), h3 = bfhi(hv.y);
            const float* w2p = W2 + (k4 * 4) * NC + wj * 10;
            #pragma unroll
            for (int j = 0; j < 10; ++j) o[j] = fmaf(h0, w2p[j], o[j]);
            #pragma unroll
            for (int j = 0; j < 10; ++j) o[j] = fmaf(h1, w2p[NC + j], o[j]);
            #pragma unroll
            for (int j = 0; j < 10; ++j) o[j] = fmaf(h2, w2p[2 * NC + j], o[j]);
            #pragma unroll
            for (int j = 0; j < 10; ++j) o[j] = fmaf(h3, w2p[3 * NC + j], o[j]);
        }
        if (row < n) {
            float* op = out + (size_t)row * NC + wj * 10;
            #pragma unroll
            for (int j = 0; j < 5; ++j)
                *(float2*)(op + j * 2) = make_float2(o[j * 2], o[j * 2 + 1]);
        }
    }
}

// ---------------- launch ----------------

extern "C" void kernel_launch(void* const* d_in, const int* in_sizes, int n_in,
                              void* d_out, int out_size, void* d_ws, size_t ws_size,
                              hipStream_t stream)
{
    const float* x  = (const float*)d_in[0];
    const int*   ei = (const int*)d_in[1];
    const float* W1 = (const float*)d_in[2];
    const float* b1 = (const float*)d_in[3];
    const float* W2 = (const float*)d_in[4];
    const float* b2 = (const float*)d_in[5];
    float* out = (float*)d_out;

    const int n = NN, E = NE;

    char* ws = (char*)d_ws;
    size_t off = 0;
    auto alloc = [&](size_t bytes) -> void* {
        void* p = ws + off;
        off = (off + bytes + 255) & ~(size_t)255;
        return p;
    };
    int*   cnt  = (int*)  alloc((size_t)n * 4);
    int*   fill = (int*)  alloc((size_t)n * 4);
    int*   rp   = (int*)  alloc((size_t)(n + 1) * 4);
    float* dinv = (float*)alloc((size_t)n * 4);
    int2*  colw = (int2*) alloc((size_t)E * 8);
    uint4* ha   = (uint4*)alloc((size_t)n * NF * 2);   // bf16 h ping
    uint4* hbuf = (uint4*)alloc((size_t)n * NF * 2);   // bf16 h pong
    float* y    = (float*)alloc((size_t)n * NF * 4);   // f32 accumulator

    hipMemsetAsync(cnt, 0, (size_t)n * 4, stream);
    hipMemsetAsync(fill, 0, (size_t)n * 4, stream);

    const int* rows = ei;
    const int* cols = ei + E;

    k_count  <<<(E + 255) / 256, 256, 0, stream>>>(rows, cnt, E);
    k_dinv   <<<(n + 255) / 256, 256, 0, stream>>>(cnt, dinv, n);
    k_scan   <<<1, 1024, 0, stream>>>(cnt, rp, n);
    k_scatter<<<(E + 255) / 256, 256, 0, stream>>>(rows, cols, rp, fill, dinv, colw, E);

    int nchunk = n * 8;  // 8-feature chunks
    k_init<<<(nchunk + 255) / 256, 256, 0, stream>>>((const float4*)x, (float4*)y, ha, nchunk);

    uint4* cur = ha;
    uint4* nxt = hbuf;
    int spmm_blocks = ((n + 1) / 2 * 64 + 255) / 256;
    for (int it = 0; it < ORDER_C; ++it) {
        k_spmm<<<spmm_blocks, 256, 0, stream>>>(cur, nxt, (float4*)y, rp, colw, dinv, n);
        uint4* t = cur; cur = nxt; nxt = t;
    }

    k_mlp<<<(n + 63) / 64, 256, 0, stream>>>((const float4*)y, W1, b1, W2, b2, out, n);
}

// Round 5
// 553.095 us; speedup vs baseline: 1.7667x; 1.2515x over previous
//
#include <hip/hip_runtime.h>

#define NN 100000
#define NE 1200000
#define NF 64
#define NH 256
#define NC 40
#define ORDER_C 8
#define SC 1024  // scan chunk (elements per block)

// ---- bf16 helpers (RTNE pack, cheap unpack) ----
__device__ __forceinline__ unsigned bf16r(float x) {
    unsigned u = __float_as_uint(x);
    return (u + 0x7FFFu + ((u >> 16) & 1u)) >> 16;
}
__device__ __forceinline__ unsigned packbf(float lo, float hi) {
    return bf16r(lo) | (bf16r(hi) << 16);
}
__device__ __forceinline__ float bflo(unsigned u) { return __uint_as_float(u << 16); }
__device__ __forceinline__ float bfhi(unsigned u) { return __uint_as_float(u & 0xFFFF0000u); }

// ---------------- CSR build ----------------

static __global__ __launch_bounds__(256) void k_count(const int* __restrict__ rows,
                                                      int* __restrict__ cnt, int E)
{
    int i = blockIdx.x * 256 + threadIdx.x;
    if (i < E) atomicAdd(&cnt[rows[i]], 1);
}

// scan phase 1: per-block sums of 1024-element chunks
static __global__ __launch_bounds__(256) void k_bsum(const int* __restrict__ cnt,
                                                     int* __restrict__ bsum, int n)
{
    __shared__ int red[256];
    int t = threadIdx.x;
    int idx = blockIdx.x * SC + t * 4;
    int s = 0;
    if (idx + 3 < n) {
        int4 q = *(const int4*)&cnt[idx];
        s = q.x + q.y + q.z + q.w;
    } else {
        for (int j = 0; j < 4; ++j) if (idx + j < n) s += cnt[idx + j];
    }
    red[t] = s;
    __syncthreads();
    for (int off = 128; off > 0; off >>= 1) {
        if (t < off) red[t] += red[t + off];
        __syncthreads();
    }
    if (t == 0) bsum[blockIdx.x] = red[0];
}

// scan phase 2: single block scans block sums (nb <= 128); also writes rp[n]=total
static __global__ __launch_bounds__(128) void k_scanb(const int* __restrict__ bsum,
                                                      int* __restrict__ boff,
                                                      int* __restrict__ rp, int nb, int n)
{
    __shared__ int red[128];
    int t = threadIdx.x;
    int v = (t < nb) ? bsum[t] : 0;
    red[t] = v;
    __syncthreads();
    for (int off = 1; off < 128; off <<= 1) {
        int x = (t >= off) ? red[t - off] : 0;
        __syncthreads();
        red[t] += x;
        __syncthreads();
    }
    if (t < nb) boff[t] = (t == 0) ? 0 : red[t - 1];
    if (t == 0) rp[n] = red[127];
}

// scan phase 3: per-block local exclusive scan + block offset -> rp; also dinv
static __global__ __launch_bounds__(256) void k_scan3(const int* __restrict__ cnt,
                                                      const int* __restrict__ boff,
                                                      int* __restrict__ rp,
                                                      float* __restrict__ dinv, int n)
{
    __shared__ int red[256];
    int t = threadIdx.x;
    int idx = blockIdx.x * SC + t * 4;
    int v[4] = {0, 0, 0, 0};
    if (idx + 3 < n) {
        int4 q = *(const int4*)&cnt[idx];
        v[0] = q.x; v[1] = q.y; v[2] = q.z; v[3] = q.w;
    } else {
        for (int j = 0; j < 4; ++j) if (idx + j < n) v[j] = cnt[idx + j];
    }
    red[t] = v[0] + v[1] + v[2] + v[3];
    __syncthreads();
    for (int off = 1; off < 256; off <<= 1) {
        int x = (t >= off) ? red[t - off] : 0;
        __syncthreads();
        red[t] += x;
        __syncthreads();
    }
    int run = ((t == 0) ? 0 : red[t - 1]) + boff[blockIdx.x];
    #pragma unroll
    for (int j = 0; j < 4; ++j) {
        if (idx + j < n) {
            rp[idx + j] = run;
            dinv[idx + j] = rsqrtf((float)(v[j] + 1));  // +1 self-loop
            run += v[j];
        }
    }
}

static __global__ __launch_bounds__(256) void k_scatter(const int* __restrict__ rows,
                                                        const int* __restrict__ cols,
                                                        const int* __restrict__ rp,
                                                        int* __restrict__ fill,
                                                        const float* __restrict__ dinv,
                                                        int2* __restrict__ colw, int E)
{
    int i = blockIdx.x * 256 + threadIdx.x;
    if (i < E) {
        int r = rows[i], c = cols[i];
        int pos = rp[r] + atomicAdd(&fill[r], 1);
        colw[pos] = make_int2(c, __float_as_int(dinv[c]));
    }
}

// ---------------- init: y = 0.5*x (f32) ; h = bf16(0.5*x) ----------------

static __global__ __launch_bounds__(256) void k_init(const float4* __restrict__ x4,
                                                     float4* __restrict__ y4,
                                                     uint4* __restrict__ hb, int nchunk)
{
    int i = blockIdx.x * 256 + threadIdx.x;
    if (i >= nchunk) return;
    float4 a = x4[i * 2], b = x4[i * 2 + 1];
    a.x *= 0.5f; a.y *= 0.5f; a.z *= 0.5f; a.w *= 0.5f;
    b.x *= 0.5f; b.y *= 0.5f; b.z *= 0.5f; b.w *= 0.5f;
    y4[i * 2] = a; y4[i * 2 + 1] = b;
    hb[i] = make_uint4(packbf(a.x, a.y), packbf(a.z, a.w),
                       packbf(b.x, b.y), packbf(b.z, b.w));
}

// ---------------- SpMM: half-wave per row, lane = u32 (2 bf16 feats) ----------------
// gather per edge = 32 lanes x 4B = one 128B line; no cross-lane reduction.

static __global__ __launch_bounds__(256) void k_spmm(const unsigned* __restrict__ hb,
                                                     unsigned* __restrict__ ho,
                                                     float2* __restrict__ y2,
                                                     const int* __restrict__ rp,
                                                     const int2* __restrict__ colw,
                                                     const float* __restrict__ dinv, int n)
{
    int wid  = (blockIdx.x * 256 + threadIdx.x) >> 6;
    int lane = threadIdx.x & 63;
    int row  = wid * 2 + (lane >> 5);
    int j    = lane & 31;            // u32 slot within the 128B bf16 row
    if (row >= n) return;
    int s = rp[row], e = rp[row + 1];

    float aL0 = 0.f, aR0 = 0.f, aL1 = 0.f, aR1 = 0.f;
    int i = s;
    for (; i + 3 < e; i += 4) {
        int2 c0 = colw[i], c1 = colw[i + 1], c2 = colw[i + 2], c3 = colw[i + 3];
        unsigned h0 = hb[c0.x * 32 + j];
        unsigned h1 = hb[c1.x * 32 + j];
        unsigned h2 = hb[c2.x * 32 + j];
        unsigned h3 = hb[c3.x * 32 + j];
        float w0 = __int_as_float(c0.y), w1 = __int_as_float(c1.y);
        float w2 = __int_as_float(c2.y), w3 = __int_as_float(c3.y);
        aL0 = fmaf(w0, bflo(h0), aL0); aR0 = fmaf(w0, bfhi(h0), aR0);
        aL1 = fmaf(w1, bflo(h1), aL1); aR1 = fmaf(w1, bfhi(h1), aR1);
        aL0 = fmaf(w2, bflo(h2), aL0); aR0 = fmaf(w2, bfhi(h2), aR0);
        aL1 = fmaf(w3, bflo(h3), aL1); aR1 = fmaf(w3, bfhi(h3), aR1);
    }
    for (; i < e; ++i) {
        int2 c = colw[i];
        unsigned h = hb[c.x * 32 + j];
        float w = __int_as_float(c.y);
        aL0 = fmaf(w, bflo(h), aL0); aR0 = fmaf(w, bfhi(h), aR0);
    }
    float accL = aL0 + aL1, accR = aR0 + aR1;

    float di = dinv[row];
    unsigned hs = hb[row * 32 + j];
    float v0 = di * fmaf(di, bflo(hs), accL);
    float v1 = di * fmaf(di, bfhi(hs), accR);
    ho[row * 32 + j] = packbf(v0, v1);
    float2 yv = y2[row * 32 + j];
    yv.x += v0; yv.y += v1;
    y2[row * 32 + j] = yv;
}

// ---------------- fused MLP: 64 rows/block, LDS-staged, broadcast weights ----------------
// out[row] = relu((y[row]/9) @ W1 + b1) @ W2 + b2

static __global__ __launch_bounds__(256) void k_mlp(const float4* __restrict__ y4,
                                                    const float* __restrict__ W1,
                                                    const float* __restrict__ b1,
                                                    const float* __restrict__ W2,
                                                    const float* __restrict__ b2,
                                                    float* __restrict__ out, int n)
{
    __shared__ float ysT[64][68];          // [feat][row], f32
    __shared__ unsigned short hs[64][268]; // [row][hid] bf16
    const float S = 1.f / 9.f;
    int t = threadIdx.x;
    int base = blockIdx.x * 64;

    {
        int r = t >> 2, fq = t & 3;
        int row = base + r;
        bool valid = row < n;
        #pragma unroll
        for (int j = 0; j < 4; ++j) {
            float4 v = valid ? y4[(size_t)row * 16 + fq * 4 + j]
                             : make_float4(0.f, 0.f, 0.f, 0.f);
            ysT[fq * 16 + j * 4 + 0][r] = v.x * S;
            ysT[fq * 16 + j * 4 + 1][r] = v.y * S;
            ysT[fq * 16 + j * 4 + 2][r] = v.z * S;
            ysT[fq * 16 + j * 4 + 3][r] = v.w * S;
        }
    }
    __syncthreads();

    int c = t & 63;
    int w = t >> 6;
    int w16 = w * 16;
    {
        float4 acc[16];
        float4 bb = ((const float4*)b1)[c];
        #pragma unroll
        for (int r = 0; r < 16; ++r) acc[r] = bb;
        const float4* W14 = (const float4*)W1;
        #pragma unroll 2
        for (int k = 0; k < 64; ++k) {
            float4 wv = W14[k * 64 + c];
            const float4* yp = (const float4*)&ysT[k][w16];
            float4 y0 = yp[0], y1 = yp[1], y2 = yp[2], y3 = yp[3];
            #pragma unroll
            for (int j = 0; j < 4; ++j) {
                float ya = (j == 0) ? y0.x : (j == 1) ? y0.y : (j == 2) ? y0.z : y0.w;
                acc[j].x = fmaf(ya, wv.x, acc[j].x);
                acc[j].y = fmaf(ya, wv.y, acc[j].y);
                acc[j].z = fmaf(ya, wv.z, acc[j].z);
                acc[j].w = fmaf(ya, wv.w, acc[j].w);
            }
            #pragma unroll
            for (int j = 0; j < 4; ++j) {
                float ya = (j == 0) ? y1.x : (j == 1) ? y1.y : (j == 2) ? y1.z : y1.w;
                acc[4 + j].x = fmaf(ya, wv.x, acc[4 + j].x);
                acc[4 + j].y = fmaf(ya, wv.y, acc[4 + j].y);
                acc[4 + j].z = fmaf(ya, wv.z, acc[4 + j].z);
                acc[4 + j].w = fmaf(ya, wv.w, acc[4 + j].w);
            }
            #pragma unroll
            for (int j = 0; j < 4; ++j) {
                float ya = (j == 0) ? y2.x : (j == 1) ? y2.y : (j == 2) ? y2.z : y2.w;
                acc[8 + j].x = fmaf(ya, wv.x, acc[8 + j].x);
                acc[8 + j].y = fmaf(ya, wv.y, acc[8 + j].y);
                acc[8 + j].z = fmaf(ya, wv.z, acc[8 + j].z);
                acc[8 + j].w = fmaf(ya, wv.w, acc[8 + j].w);
            }
            #pragma unroll
            for (int j = 0; j < 4; ++j) {
                float ya = (j == 0) ? y3.x : (j == 1) ? y3.y : (j == 2) ? y3.z : y3.w;
                acc[12 + j].x = fmaf(ya, wv.x, acc[12 + j].x);
                acc[12 + j].y = fmaf(ya, wv.y, acc[12 + j].y);
                acc[12 + j].z = fmaf(ya, wv.z, acc[12 + j].z);
                acc[12 + j].w = fmaf(ya, wv.w, acc[12 + j].w);
            }
        }
        #pragma unroll
        for (int r = 0; r < 16; ++r) {
            float hx = fmaxf(acc[r].x, 0.f), hy = fmaxf(acc[r].y, 0.f);
            float hz = fmaxf(acc[r].z, 0.f), hw = fmaxf(acc[r].w, 0.f);
            uint2 p = make_uint2(packbf(hx, hy), packbf(hz, hw));
            *(uint2*)&hs[w16 + r][c * 4] = p;
        }
    }
    __syncthreads();

    {
        int r2 = t & 63;
        int wj = __builtin_amdgcn_readfirstlane(t >> 6);
        int row = base + r2;
        float o[10];
        #pragma unroll
        for (int j = 0; j < 10; ++j) o[j] = b2[wj * 10 + j];
        #pragma unroll 2
        for (int k4 = 0; k4 < 64; ++k4) {
            uint2 hv = *(const uint2*)&hs[r2][k4 * 4];
            float h0 = bflo(hv.x), h1 = bfhi(hv.x);
            float h2 = bflo(hv.y), h3 = bfhi(hv.y);
            const float* w2p = W2 + (k4 * 4) * NC + wj * 10;
            #pragma unroll
            for (int j = 0; j < 10; ++j) o[j] = fmaf(h0, w2p[j], o[j]);
            #pragma unroll
            for (int j = 0; j < 10; ++j) o[j] = fmaf(h1, w2p[NC + j], o[j]);
            #pragma unroll
            for (int j = 0; j < 10; ++j) o[j] = fmaf(h2, w2p[2 * NC + j], o[j]);
            #pragma unroll
            for (int j = 0; j < 10; ++j) o[j] = fmaf(h3, w2p[3 * NC + j], o[j]);
        }
        if (row < n) {
            float* op = out + (size_t)row * NC + wj * 10;
            #pragma unroll
            for (int j = 0; j < 5; ++j)
                *(float2*)(op + j * 2) = make_float2(o[j * 2], o[j * 2 + 1]);
        }
    }
}

// ---------------- launch ----------------

extern "C" void kernel_launch(void* const* d_in, const int* in_sizes, int n_in,
                              void* d_out, int out_size, void* d_ws, size_t ws_size,
                              hipStream_t stream)
{
    const float* x  = (const float*)d_in[0];
    const int*   ei = (const int*)d_in[1];
    const float* W1 = (const float*)d_in[2];
    const float* b1 = (const float*)d_in[3];
    const float* W2 = (const float*)d_in[4];
    const float* b2 = (const float*)d_in[5];
    float* out = (float*)d_out;

    const int n = NN, E = NE;
    const int nb = (n + SC - 1) / SC;  // 98 scan blocks

    char* ws = (char*)d_ws;
    size_t off = 0;
    auto alloc = [&](size_t bytes) -> void* {
        void* p = ws + off;
        off = (off + bytes + 255) & ~(size_t)255;
        return p;
    };
    int*   cnt  = (int*)  alloc((size_t)n * 4);
    int*   fill = (int*)  alloc((size_t)n * 4);
    int*   rp   = (int*)  alloc((size_t)(n + 1) * 4);
    float* dinv = (float*)alloc((size_t)n * 4);
    int*   bsum = (int*)  alloc(128 * 4);
    int*   boff = (int*)  alloc(128 * 4);
    int2*  colw = (int2*) alloc((size_t)E * 8);
    uint4* ha   = (uint4*)alloc((size_t)n * NF * 2);   // bf16 h ping
    uint4* hbuf = (uint4*)alloc((size_t)n * NF * 2);   // bf16 h pong
    float* y    = (float*)alloc((size_t)n * NF * 4);   // f32 accumulator

    hipMemsetAsync(cnt, 0, (size_t)n * 4, stream);
    hipMemsetAsync(fill, 0, (size_t)n * 4, stream);

    const int* rows = ei;
    const int* cols = ei + E;

    k_count  <<<(E + 255) / 256, 256, 0, stream>>>(rows, cnt, E);
    k_bsum   <<<nb, 256, 0, stream>>>(cnt, bsum, n);
    k_scanb  <<<1, 128, 0, stream>>>(bsum, boff, rp, nb, n);
    k_scan3  <<<nb, 256, 0, stream>>>(cnt, boff, rp, dinv, n);
    k_scatter<<<(E + 255) / 256, 256, 0, stream>>>(rows, cols, rp, fill, dinv, colw, E);

    int nchunk = n * 8;
    k_init<<<(nchunk + 255) / 256, 256, 0, stream>>>((const float4*)x, (float4*)y, ha, nchunk);

    uint4* cur = ha;
    uint4* nxt = hbuf;
    int spmm_blocks = ((n + 1) / 2 * 64 + 255) / 256;
    for (int it = 0; it < ORDER_C; ++it) {
        k_spmm<<<spmm_blocks, 256, 0, stream>>>((const unsigned*)cur, (unsigned*)nxt,
                                                (float2*)y, rp, colw, dinv, n);
        uint4* t = cur; cur = nxt; nxt = t;
    }

    k_mlp<<<(n + 63) / 64, 256, 0, stream>>>((const float4*)y, W1, b1, W2, b2, out, n);
}